// Round 7
// baseline (137.840 us; speedup 1.0000x reference)
//
#include <hip/hip_runtime.h>
#include <stdint.h>

#define NN   4096
#define KK   32
#define HID  128
#define BLK  256
#define CAP  256

typedef unsigned short bf16_t;
typedef __attribute__((ext_vector_type(8))) short bf16x8;
typedef __attribute__((ext_vector_type(4))) float f32x4;

__device__ __forceinline__ bf16_t f2bf(float f) {
    uint32_t u = __float_as_uint(f);
    u = u + 0x7fffu + ((u >> 16) & 1u);   // round-to-nearest-even
    return (bf16_t)(u >> 16);
}
__device__ __forceinline__ float siluf(float x) {
    return x / (1.0f + __expf(-x));
}

// ---- prepack: W2 fp32 -> bf16, laid out in MFMA B-fragment order ----
// chunk c (0..2047): frag f=c>>6 (= (nh*4+nt)*4+kk), lane=c&63.
// contents: W2[row = nh*64+nt*16+(lane&15)][k = kk*32+(lane>>4)*8 .. +8]
__global__ __launch_bounds__(BLK) void prepack_w2(
    const float* __restrict__ W2, uint4* __restrict__ w2b)
{
    int c  = blockIdx.x * BLK + threadIdx.x;
    int f  = c >> 6, ln = c & 63;
    int nh = f >> 4, nt = (f >> 2) & 3, kk = f & 3;
    int row = nh*64 + nt*16 + (ln & 15);
    int k0  = kk*32 + (ln >> 4) * 8;
    const float* s = W2 + row * HID + k0;
    float4 lo = *(const float4*)s;
    float4 hi = *(const float4*)(s + 4);
    uint4 pk;
    pk.x = (uint32_t)f2bf(lo.x) | ((uint32_t)f2bf(lo.y) << 16);
    pk.y = (uint32_t)f2bf(lo.z) | ((uint32_t)f2bf(lo.w) << 16);
    pk.z = (uint32_t)f2bf(hi.x) | ((uint32_t)f2bf(hi.y) << 16);
    pk.w = (uint32_t)f2bf(hi.z) | ((uint32_t)f2bf(hi.w) << 16);
    w2b[c] = pk;
}

template<bool WS>
struct __align__(16) Sm {
    union __align__(16) {                 // phase-disjoint reuse
        uint32_t hist[1024];              // 4 KB  (dist phase)
        unsigned long long cand[CAP];     // 2 KB  (selection)
        ushort h1[KK * HID];              // 8 KB  (MLP: bf16, 16B chunks ^(edge&15))
    } u;
    uint32_t w2l[WS ? 4 : HID * 64];      // only the no-workspace fallback stages W2
    float ssq[2][KK];
    float sedge[2][KK];
    int recvs[KK];
    float wtr[4][3];
    int waveTot[4];
    unsigned long long redk[4];
    int pivotB;
    int cnt;
    int chosen;
};

template<bool WS>
__global__ __launch_bounds__(BLK) void egnn_main(
    const float* __restrict__ pos, const float* __restrict__ tptr,
    const float* __restrict__ W1,  const float* __restrict__ b1,
    const float* __restrict__ g1,  const float* __restrict__ W2,
    const float* __restrict__ b2,  const float* __restrict__ g2,
    const float* __restrict__ W3,  const float* __restrict__ b3,
    const uint4* __restrict__ w2b, float* __restrict__ out)
{
    __shared__ Sm<WS> sm;
    const int tid  = threadIdx.x;
    const int lane = tid & 63;
    const int wid  = tid >> 6;
    const int i    = blockIdx.x;
    const int l15  = lane & 15, lq = lane >> 4;
    const int mh   = wid & 1,   nh = wid >> 1;   // MFMA tile role

    // ---- layer-1 per-lane constants: neurons 2*lane, 2*lane+1 (adjacent pair) ----
    const float ts   = tptr[0];
    const float4 w1v = ((const float4*)W1)[lane];     // rows 2l,2l+1: (a0,b0,a1,b1)
    const float2 b1v = ((const float2*)b1)[lane];
    const float2 g1v = ((const float2*)g1)[lane];
    const float tc0  = ts * w1v.y + b1v.x;
    const float tc1  = ts * w1v.w + b1v.y;
    const float b3s  = b3[0];
    // ---- epilogue per-lane constants (MFMA D-layout: n = nh*64 + nt*16 + l15) ----
    float g2v[4], w3v[4], b2v[4];
    #pragma unroll
    for (int nt = 0; nt < 4; ++nt) {
        int n = nh*64 + nt*16 + l15;
        g2v[nt] = g2[n]; w3v[nt] = W3[n]; b2v[nt] = b2[n];
    }

    if constexpr (!WS) {
        // fallback: stage W2 into LDS (bf16, 16B chunks XOR-swizzled by row&15)
        for (int idx = tid; idx < HID * 16; idx += BLK) {
            int row = idx >> 4, c = idx & 15;
            const float* src = W2 + row * HID + c * 8;
            float4 lo = *(const float4*)src;
            float4 hi = *(const float4*)(src + 4);
            uint4 pk;
            pk.x = (uint32_t)f2bf(lo.x) | ((uint32_t)f2bf(lo.y) << 16);
            pk.y = (uint32_t)f2bf(lo.z) | ((uint32_t)f2bf(lo.w) << 16);
            pk.z = (uint32_t)f2bf(hi.x) | ((uint32_t)f2bf(hi.y) << 16);
            pk.w = (uint32_t)f2bf(hi.z) | ((uint32_t)f2bf(hi.w) << 16);
            *((uint4*)&sm.w2l[row * 64 + 4 * (c ^ (row & 15))]) = pk;
        }
    }
    ((uint4*)sm.u.hist)[tid] = uint4{0u, 0u, 0u, 0u};   // 1024 dwords, one uint4/thread
    if (tid == 0) sm.cnt = 0;
    __syncthreads();

    const float px = pos[3*i], py = pos[3*i+1], pz = pos[3*i+2];

    // ---- distances into REGISTERS (exact fp32 chain) + LDS histogram ----
    // thread covers j = 1024*g + 4*tid + c  (g<4, c<4); pos read as 3x float4.
    // self-distance computes to exactly 0.0 (bucket 0) and is patched afterwards.
    float dreg[4][4];
    {
        const float4* p4 = (const float4*)pos;
        #pragma unroll
        for (int g = 0; g < 4; ++g) {
            float4 f0 = p4[768*g + 3*tid];
            float4 f1 = p4[768*g + 3*tid + 1];
            float4 f2 = p4[768*g + 3*tid + 2];
            float jx[4] = {f0.x, f0.w, f1.z, f2.y};
            float jy[4] = {f0.y, f1.x, f1.w, f2.z};
            float jz[4] = {f0.z, f1.y, f2.x, f2.w};
            #pragma unroll
            for (int c = 0; c < 4; ++c) {
                float dx = px - jx[c];
                float dy = py - jy[c];
                float dz = pz - jz[c];
                float d = __fadd_rn(__fadd_rn(__fmul_rn(dx,dx), __fmul_rn(dy,dy)),
                                    __fmul_rn(dz,dz));
                dreg[g][c] = d;
                atomicAdd((int*)&sm.u.hist[__float_as_uint(d) >> 21], 1);
            }
        }
    }
    if (((i & 1023) >> 2) == tid) dreg[i >> 10][i & 3] = __uint_as_float(0x7f800000u);
    if (tid == 0) atomicAdd((int*)&sm.u.hist[0], -1);   // remove self's bucket-0 entry
    __syncthreads();

    // ---- pivot bucket B: first bucket where cumulative count >= KK ----
    {
        const int b0 = tid * 4;
        int h0 = (int)sm.u.hist[b0],   hA = (int)sm.u.hist[b0+1];
        int h2 = (int)sm.u.hist[b0+2], h3 = (int)sm.u.hist[b0+3];
        int s = h0 + hA + h2 + h3;
        int incl = s;
        #pragma unroll
        for (int off = 1; off < 64; off <<= 1) {
            int v = __shfl_up(incl, off, 64);
            if (lane >= off) incl += v;
        }
        if (lane == 63) sm.waveTot[wid] = incl;
        __syncthreads();
        int base = 0;
        for (int w = 0; w < wid; ++w) base += sm.waveTot[w];
        int E = base + incl - s;
        if (E < KK && E + s >= KK) {
            int cum = E, B = b0 + 3;
            if (cum + h0 >= KK) B = b0;
            else { cum += h0;
                if (cum + hA >= KK) B = b0 + 1;
                else { cum += hA;
                    if (cum + h2 >= KK) B = b0 + 2;
                }
            }
            sm.pivotB = B;
        }
    }
    __syncthreads();

    // ---- compaction from registers: keys with bucket <= B (cand aliases hist) ----
    {
        const int B = sm.pivotB;
        #pragma unroll
        for (int g = 0; g < 4; ++g) {
            #pragma unroll
            for (int c = 0; c < 4; ++c) {
                uint32_t ub = __float_as_uint(dreg[g][c]);   // self=inf -> bucket 1020 > B
                if ((int)(ub >> 21) <= B) {
                    int slot = atomicAdd(&sm.cnt, 1);
                    if (slot < CAP)
                        sm.u.cand[slot] = (((unsigned long long)ub) << 12)
                                        | (unsigned)(1024*g + 4*tid + c);
                }
            }
        }
    }
    __syncthreads();

    const int cnt = sm.cnt;
    if (cnt <= CAP) {
        if (tid < cnt) {
            unsigned long long km = sm.u.cand[tid];
            int rank = 0;
            for (int q = 0; q < cnt; ++q)
                rank += (sm.u.cand[q] < km) ? 1 : 0;
            if (rank < KK) sm.recvs[rank] = (int)(km & 0xFFFull);
        }
    } else {
        // fallback (tie overflow; essentially never): exact 32-pass argmin over regs
        for (int it = 0; it < KK; ++it) {
            unsigned long long best = ~0ull;
            #pragma unroll
            for (int g = 0; g < 4; ++g)
                #pragma unroll
                for (int c = 0; c < 4; ++c) {
                    unsigned long long key =
                        (((unsigned long long)__float_as_uint(dreg[g][c])) << 12)
                        | (unsigned)(1024*g + 4*tid + c);
                    best = best < key ? best : key;
                }
            #pragma unroll
            for (int m = 32; m >= 1; m >>= 1) {
                unsigned long long o = __shfl_xor(best, m, 64);
                best = best < o ? best : o;
            }
            if (lane == 0) sm.redk[wid] = best;
            __syncthreads();
            if (tid == 0) {
                unsigned long long b01 = sm.redk[0] < sm.redk[1] ? sm.redk[0] : sm.redk[1];
                unsigned long long b23 = sm.redk[2] < sm.redk[3] ? sm.redk[2] : sm.redk[3];
                unsigned long long b   = b01 < b23 ? b01 : b23;
                int j = (int)(b & 0xfffull);
                sm.recvs[it] = j;
                sm.chosen = j;
            }
            __syncthreads();
            int j = sm.chosen;
            if (((j & 1023) >> 2) == tid)
                dreg[j >> 10][j & 3] = __uint_as_float(0x7f800000u);
        }
    }
    __syncthreads();   // recvs visible; hist/cand dead (h1 will overwrite union)

    // ---- geometry + layer 1: wave owns edges [8*wid, 8*wid+8) ----
    const int eb = wid * 8;
    float cdx[8], cdy[8], cdz[8];
    {
        float p0v[8], p1v[8], sq[8];
        #pragma unroll
        for (int e = 0; e < 8; ++e) {
            int r = sm.recvs[eb + e];
            float dx = px - pos[3*r];
            float dy = py - pos[3*r+1];
            float dz = pz - pos[3*r+2];
            cdx[e] = dx; cdy[e] = dy; cdz[e] = dz;
            float rad = __fadd_rn(__fadd_rn(__fmul_rn(dx,dx), __fmul_rn(dy,dy)),
                                  __fmul_rn(dz,dz));
            float p0 = rad * w1v.x + tc0;
            float p1 = rad * w1v.z + tc1;
            p0v[e] = p0; p1v[e] = p1;
            sq[e] = p0*p0 + p1*p1;
        }
        #pragma unroll
        for (int m = 32; m >= 1; m >>= 1) {
            #pragma unroll
            for (int e = 0; e < 8; ++e) sq[e] += __shfl_xor(sq[e], m, 64);
        }
        // h1 bf16 [32][128], 16B chunks swizzled by ^(edge&15); neuron pair (2l,2l+1)
        // packed into one b32 (truncation-rounded bf16 - well under tolerance)
        uint32_t* h1d = (uint32_t*)sm.u.h1;
        const int ch = lane >> 2, dw = lane & 3;
        #pragma unroll
        for (int e = 0; e < 8; ++e) {
            float rn = rsqrtf(sq[e] * (1.0f/HID) + 1e-5f);
            float a = siluf(p0v[e] * rn * g1v.x);
            float b = siluf(p1v[e] * rn * g1v.y);
            uint32_t pk = (__float_as_uint(a) >> 16) | (__float_as_uint(b) & 0xffff0000u);
            int ge = eb + e;
            h1d[ge*64 + ((ch ^ (ge & 15)))*4 + dw] = pk;
        }
    }
    __syncthreads();

    // ---- layer 2 via MFMA: A from LDS h1; B from global (WS) or LDS (fallback) ----
    f32x4 acc0 = {0.f,0.f,0.f,0.f}, acc1 = acc0, acc2 = acc0, acc3 = acc0;
    {
        const bf16x8* h1v = (const bf16x8*)sm.u.h1;   // [32][16 chunks]
        const int m = mh*16 + l15;
        if constexpr (WS) {
            const bf16x8* bv = (const bf16x8*)w2b;
            #pragma unroll
            for (int kk = 0; kk < 4; ++kk) {
                bf16x8 af = h1v[m*16 + ((kk*4 + lq) ^ l15)];
                acc0 = __builtin_amdgcn_mfma_f32_16x16x32_bf16(
                           af, bv[((nh*4+0)*4 + kk)*64 + lane], acc0, 0, 0, 0);
                acc1 = __builtin_amdgcn_mfma_f32_16x16x32_bf16(
                           af, bv[((nh*4+1)*4 + kk)*64 + lane], acc1, 0, 0, 0);
                acc2 = __builtin_amdgcn_mfma_f32_16x16x32_bf16(
                           af, bv[((nh*4+2)*4 + kk)*64 + lane], acc2, 0, 0, 0);
                acc3 = __builtin_amdgcn_mfma_f32_16x16x32_bf16(
                           af, bv[((nh*4+3)*4 + kk)*64 + lane], acc3, 0, 0, 0);
            }
        } else {
            const bf16x8* w2v = (const bf16x8*)sm.w2l;    // [128][16 chunks]
            const int nrow0 = (nh*64 +      l15) * 16;
            const int nrow1 = (nh*64 + 16 + l15) * 16;
            const int nrow2 = (nh*64 + 32 + l15) * 16;
            const int nrow3 = (nh*64 + 48 + l15) * 16;
            #pragma unroll
            for (int kk = 0; kk < 4; ++kk) {
                const int q = (kk*4 + lq) ^ l15;
                bf16x8 af = h1v[m*16 + q];
                acc0 = __builtin_amdgcn_mfma_f32_16x16x32_bf16(af, w2v[nrow0 + q], acc0, 0, 0, 0);
                acc1 = __builtin_amdgcn_mfma_f32_16x16x32_bf16(af, w2v[nrow1 + q], acc1, 0, 0, 0);
                acc2 = __builtin_amdgcn_mfma_f32_16x16x32_bf16(af, w2v[nrow2 + q], acc2, 0, 0, 0);
                acc3 = __builtin_amdgcn_mfma_f32_16x16x32_bf16(af, w2v[nrow3 + q], acc3, 0, 0, 0);
            }
        }
    }

    // z[nt][r]: pre-norm layer-2 out for (edge mh*16+lq*4+r, neuron nh*64+nt*16+l15)
    float z[4][4];
    #pragma unroll
    for (int r = 0; r < 4; ++r) {
        z[0][r] = acc0[r] + b2v[0];
        z[1][r] = acc1[r] + b2v[1];
        z[2][r] = acc2[r] + b2v[2];
        z[3][r] = acc3[r] + b2v[3];
    }

    float ss[4];
    #pragma unroll
    for (int r = 0; r < 4; ++r)
        ss[r] = z[0][r]*z[0][r] + z[1][r]*z[1][r] + z[2][r]*z[2][r] + z[3][r]*z[3][r];
    #pragma unroll
    for (int m = 8; m >= 1; m >>= 1) {
        #pragma unroll
        for (int r = 0; r < 4; ++r) ss[r] += __shfl_xor(ss[r], m, 64);
    }
    if (l15 == 0) {
        #pragma unroll
        for (int r = 0; r < 4; ++r) sm.ssq[nh][mh*16 + lq*4 + r] = ss[r];
    }
    __syncthreads();

    float sp[4];
    #pragma unroll
    for (int r = 0; r < 4; ++r) {
        int e = mh*16 + lq*4 + r;
        float rn = rsqrtf((sm.ssq[0][e] + sm.ssq[1][e]) * (1.0f/HID) + 1e-5f);
        sp[r] = siluf(z[0][r] * rn * g2v[0]) * w3v[0]
              + siluf(z[1][r] * rn * g2v[1]) * w3v[1]
              + siluf(z[2][r] * rn * g2v[2]) * w3v[2]
              + siluf(z[3][r] * rn * g2v[3]) * w3v[3];
    }
    #pragma unroll
    for (int m = 8; m >= 1; m >>= 1) {
        #pragma unroll
        for (int r = 0; r < 4; ++r) sp[r] += __shfl_xor(sp[r], m, 64);
    }
    if (l15 == 0) {
        #pragma unroll
        for (int r = 0; r < 4; ++r) sm.sedge[nh][mh*16 + lq*4 + r] = sp[r];
    }
    __syncthreads();

    // ---- final: edge scalar -> message accumulate (geometry wave owns cd) ----
    float a3x = 0.f, a3y = 0.f, a3z = 0.f;
    #pragma unroll
    for (int e = 0; e < 8; ++e) {
        int ge = eb + e;
        float s = sm.sedge[0][ge] + sm.sedge[1][ge] + b3s;
        a3x += cdx[e]*s; a3y += cdy[e]*s; a3z += cdz[e]*s;
    }
    if (lane == 0) { sm.wtr[wid][0] = a3x; sm.wtr[wid][1] = a3y; sm.wtr[wid][2] = a3z; }
    __syncthreads();
    if (tid < 3) {
        float v = pos[3*i + tid] +
                  (sm.wtr[0][tid] + sm.wtr[1][tid] + sm.wtr[2][tid] + sm.wtr[3][tid]) * (1.0f/KK);
        out[3*i + tid] = v;
    }
}

extern "C" void kernel_launch(void* const* d_in, const int* in_sizes, int n_in,
                              void* d_out, int out_size, void* d_ws, size_t ws_size,
                              hipStream_t stream) {
    (void)in_sizes; (void)n_in; (void)out_size;
    const float* pos = (const float*)d_in[0];
    const float* t   = (const float*)d_in[1];
    const float* W1  = (const float*)d_in[2];
    const float* b1  = (const float*)d_in[3];
    const float* g1  = (const float*)d_in[4];
    const float* W2  = (const float*)d_in[5];
    const float* b2  = (const float*)d_in[6];
    const float* g2  = (const float*)d_in[7];
    const float* W3  = (const float*)d_in[8];
    const float* b3  = (const float*)d_in[9];
    float* out = (float*)d_out;

    if (d_ws != nullptr && ws_size >= 32768) {
        prepack_w2<<<8, BLK, 0, stream>>>(W2, (uint4*)d_ws);
        egnn_main<true><<<NN, BLK, 0, stream>>>(
            pos, t, W1, b1, g1, W2, b2, g2, W3, b3, (const uint4*)d_ws, out);
    } else {
        egnn_main<false><<<NN, BLK, 0, stream>>>(
            pos, t, W1, b1, g1, W2, b2, g2, W3, b3, nullptr, out);
    }
}